// Round 7
// baseline (64.555 us; speedup 1.0000x reference)
//
#include <hip/hip_runtime.h>
#include <hip/hip_bf16.h>

#define BB 4096
#define DD 512

typedef unsigned short u16;
typedef unsigned int u32;

using f32x4 = __attribute__((ext_vector_type(4))) float;
using bf16x8 = __attribute__((ext_vector_type(8))) short;

// exp scaling: p = exp2((s-1)*100*log2e + 64)  -> all normal-range for s in [-0.44, 1]
// lse = 100 - 64*ln2 + ln(sum p)
constexpr float CEXP = 144.26950408889634f;          // 100 * log2(e)
constexpr float EOFF = 64.0f - 144.26950408889634f;  // bias - CEXP
constexpr float LN2 = 0.6931471805599453f;
constexpr float LSE_BASE = 100.0f - 64.0f * 0.6931471805599453f;

__device__ __forceinline__ float wave_sum(float v) {
#pragma unroll
  for (int m = 1; m < 64; m <<= 1) v += __shfl_xor(v, m);
  return v;
}

__device__ __forceinline__ u16 f2bf(float f) {
  __hip_bfloat16 h = __float2bfloat16(f);
  return __builtin_bit_cast(u16, h);
}

// async global->LDS, 16B per lane. LDS dest must be wave-uniform; HW adds lane*16.
__device__ __forceinline__ void gload16(const u16* g, const u16* l) {
  __builtin_amdgcn_global_load_lds(
      (const __attribute__((address_space(1))) void*)g,
      (__attribute__((address_space(3))) void*)(const_cast<u16*>(l)), 16, 0, 0);
}

// raw barrier (no vmcnt/lgkmcnt drain); memory clobbers pin memory ops to their side
__device__ __forceinline__ void barrier_raw() {
  asm volatile("" ::: "memory");
  __builtin_amdgcn_s_barrier();
  asm volatile("" ::: "memory");
}

// ---------------- kernel 1: row L2-normalize (fp32) -> bf16, plus fp32 pos ----------------
__global__ __launch_bounds__(256) void k_norm(const float* __restrict__ feat,
                                              const float* __restrict__ feat_old,
                                              u16* __restrict__ fnb, u16* __restrict__ fob,
                                              float* __restrict__ pos) {
  const int i = blockIdx.x * 4 + (threadIdx.x >> 6);
  const int t = threadIdx.x & 63;
  const float4 x0 = *(const float4*)(feat + (size_t)i * DD + t * 4);
  const float4 x1 = *(const float4*)(feat + (size_t)i * DD + 256 + t * 4);
  const float4 y0 = *(const float4*)(feat_old + (size_t)i * DD + t * 4);
  const float4 y1 = *(const float4*)(feat_old + (size_t)i * DD + 256 + t * 4);
  float sx = x0.x * x0.x + x0.y * x0.y + x0.z * x0.z + x0.w * x0.w +
             x1.x * x1.x + x1.y * x1.y + x1.z * x1.z + x1.w * x1.w;
  float sy = y0.x * y0.x + y0.y * y0.y + y0.z * y0.z + y0.w * y0.w +
             y1.x * y1.x + y1.y * y1.y + y1.z * y1.z + y1.w * y1.w;
  float sxy = x0.x * y0.x + x0.y * y0.y + x0.z * y0.z + x0.w * y0.w +
              x1.x * y1.x + x1.y * y1.y + x1.z * y1.z + x1.w * y1.w;
  sx = wave_sum(sx);
  sy = wave_sum(sy);
  sxy = wave_sum(sxy);
  const float inx = 1.0f / fmaxf(sqrtf(sx), 1e-12f);
  const float iny = 1.0f / fmaxf(sqrtf(sy), 1e-12f);
  ushort4 ox0, ox1, oy0, oy1;
  ox0.x = f2bf(x0.x * inx); ox0.y = f2bf(x0.y * inx);
  ox0.z = f2bf(x0.z * inx); ox0.w = f2bf(x0.w * inx);
  ox1.x = f2bf(x1.x * inx); ox1.y = f2bf(x1.y * inx);
  ox1.z = f2bf(x1.z * inx); ox1.w = f2bf(x1.w * inx);
  oy0.x = f2bf(y0.x * iny); oy0.y = f2bf(y0.y * iny);
  oy0.z = f2bf(y0.z * iny); oy0.w = f2bf(y0.w * iny);
  oy1.x = f2bf(y1.x * iny); oy1.y = f2bf(y1.y * iny);
  oy1.z = f2bf(y1.z * iny); oy1.w = f2bf(y1.w * iny);
  *(ushort4*)(fnb + (size_t)i * DD + t * 4) = ox0;
  *(ushort4*)(fnb + (size_t)i * DD + 256 + t * 4) = ox1;
  *(ushort4*)(fob + (size_t)i * DD + t * 4) = oy0;
  *(ushort4*)(fob + (size_t)i * DD + 256 + t * 4) = oy1;
  if (t == 0) pos[i] = sxy * inx * iny;
}

// ---------------- kernel 2: fused dual-GEMM, m201-style 4-phase/K-tile pipeline ----------------
// 512 blocks, XCD-rect partition (rect = 4mt x 8nt, 3MB L2-fit; FETCH ~14MB proven R5/R6).
// 512 threads = 8 waves (2M x 4N); per-wave output 128 x 64 of the 256x256 virtual tile
// (vcols 0-127 = fob = n2o, 128-255 = fnb = n2n). BK=64, 8 K-tiles, 4 phases each.
// LDS: 2 parity x 4 slots {A-k0, A-k1, B-k0, B-k1} x 16KB = 128 KB.
// Phase = { ds_read subtile (4-8 x b128) ; stage 1 slot (2 x gload_lds) ; barrier ;
//           setprio(1) 16 MFMA setprio(0) ; barrier }.
// Stage lead-5 phases; gate = { vmcnt(4) ; barrier } at each K-tile boundary (race-free:
// every wave passes its own vmcnt BEFORE the barrier, so all stages landed when anyone
// proceeds). vmcnt never drains to 0 until the last gate.
__global__ __launch_bounds__(512, 2) void k_fused(const u16* __restrict__ fnb,
                                                  const u16* __restrict__ fob,
                                                  const int* __restrict__ tgt,
                                                  float* __restrict__ partial) {
  __shared__ __align__(16) u16 lds[2 * 4 * 8192];  // 128 KB

  const int tid = threadIdx.x;
  const int lane = tid & 63;
  const int wid = tid >> 6;  // 0..7
  const int wm = wid >> 2;   // 0..1  M half (128 rows)
  const int wn = wid & 3;    // 0..3  N quarter (64 of 256 virtual cols)
  const int lrow = lane & 15;
  const int lkg = lane >> 4;

  // rect partition: XCD x (blockIdx%8) owns rects {x, x+8}; rect = 4mt x 8nt
  const int flat = blockIdx.x;
  const int xcd = flat & 7, loc = flat >> 3;
  const int rnd = loc >> 5, w = loc & 31;
  const int rid = xcd + 8 * rnd;
  const int mt = (rid >> 2) * 4 + (w >> 3);
  const int nt = (rid & 3) * 8 + (w & 7);
  const int row0 = mt * 256, jb = nt * 128;

  // stage geometry: slot = 256 rows x 32 k (16 KB) = 16 chunks x (16 rows x 4 ksub);
  // wave stages chunks {2w, 2w+1}. k-sub pre-swizzled at the SOURCE so the linear LDS
  // write lands where the swizzled read expects it: phys = logical ^ (r&3) ^ ((r>>2)&3).
  const int lr = lane >> 2;  // row within chunk
  const int lc = lane & 3;   // physical k-sub

  auto stage_slot = [&](int tt, int slotId) {  // 0=A-k0 1=A-k1 2=B-k0 3=B-k1
    const u32 base = ((u32)(tt & 1) * 4 + (u32)slotId) * 8192u;
    const int kb = tt * 64 + (slotId & 1) * 32;
    const bool isA = slotId < 2;
#pragma unroll
    for (int i = 0; i < 2; ++i) {
      const int c = wid * 2 + i;
      const int r = c * 16 + lr;  // LDS row 0..255
      const int sl = lc ^ (r & 3) ^ ((r >> 2) & 3);
      const u16* src;
      if (isA) src = fnb + (size_t)(row0 + r) * DD + kb + sl * 8;
      else if (c < 8) src = fob + (size_t)(jb + r) * DD + kb + sl * 8;
      else src = fnb + (size_t)(jb + r - 128) * DD + kb + sl * 8;
      gload16(src, lds + base + (u32)c * 512u);
    }
  };

  f32x4 acc[8][4];
#pragma unroll
  for (int a = 0; a < 8; ++a)
#pragma unroll
    for (int b = 0; b < 4; ++b) acc[a][b] = (f32x4)(0.0f);

  bf16x8 av[4], bv[4];
  auto ldA = [&](int tt, int kh, int mq) {
    const char* base = (const char*)(lds + ((u32)(tt & 1) * 4 + (u32)kh) * 8192u);
#pragma unroll
    for (int mf = 0; mf < 4; ++mf) {
      const int r = wm * 128 + mq * 64 + mf * 16 + lrow;
      av[mf] = *(const bf16x8*)(base + r * 64 + ((lkg ^ (r & 3) ^ ((r >> 2) & 3)) * 16));
    }
  };
  auto ldB = [&](int tt, int kh) {
    const char* base = (const char*)(lds + ((u32)(tt & 1) * 4 + 2u + (u32)kh) * 8192u);
#pragma unroll
    for (int nf = 0; nf < 4; ++nf) {
      const int r = wn * 64 + nf * 16 + lrow;
      bv[nf] = *(const bf16x8*)(base + r * 64 + ((lkg ^ (r & 3) ^ ((r >> 2) & 3)) * 16));
    }
  };
  auto mfma16 = [&](int mq) {
    __builtin_amdgcn_s_setprio(1);
#pragma unroll
    for (int mf = 0; mf < 4; ++mf)
#pragma unroll
      for (int nf = 0; nf < 4; ++nf)
        acc[mq * 4 + mf][nf] =
            __builtin_amdgcn_mfma_f32_16x16x32_bf16(av[mf], bv[nf], acc[mq * 4 + mf][nf], 0, 0, 0);
    __builtin_amdgcn_s_setprio(0);
  };

  // prologue: tile0 all slots + tile1 {A-k0, B-k0}; gate allows the last 2 slots to fly
  stage_slot(0, 0);
  stage_slot(0, 2);
  stage_slot(0, 1);
  stage_slot(0, 3);
  stage_slot(1, 0);
  stage_slot(1, 2);
  asm volatile("s_waitcnt vmcnt(4)" ::: "memory");
  barrier_raw();

#pragma unroll
  for (int t = 0; t < 8; ++t) {
    // phase 0: (k0, mq0) ; stage A-k1(t+1)
    ldB(t, 0);
    ldA(t, 0, 0);
    if (t + 1 < 8) stage_slot(t + 1, 1);
    barrier_raw();
    mfma16(0);
    barrier_raw();
    // phase 1: (k0, mq1) ; stage B-k1(t+1)
    ldA(t, 0, 1);
    if (t + 1 < 8) stage_slot(t + 1, 3);
    barrier_raw();
    mfma16(1);
    barrier_raw();
    // phase 2: (k1, mq0) ; stage A-k0(t+2)
    ldB(t, 1);
    ldA(t, 1, 0);
    if (t + 2 < 8) stage_slot(t + 2, 0);
    barrier_raw();
    mfma16(0);
    barrier_raw();
    // phase 3: (k1, mq1) ; stage B-k0(t+2) ; K-tile gate
    ldA(t, 1, 1);
    if (t + 2 < 8) stage_slot(t + 2, 2);
    barrier_raw();
    mfma16(1);
    if (t < 6) {
      asm volatile("s_waitcnt vmcnt(4)" ::: "memory");  // next tile landed; 2 slots fly on
    } else if (t == 6) {
      asm volatile("s_waitcnt vmcnt(0)" ::: "memory");  // last tile: full drain
    }
    barrier_raw();
  }

  // ---- epilogue: masked exp2, col-reduce over 16 lanes, combine waves via LDS ----
  const bool isN2O = (wn < 2);
  int tc[4];
#pragma unroll
  for (int nf = 0; nf < 4; ++nf) tc[nf] = tgt[jb + (wn & 1) * 64 + nf * 16 + lrow];
  float* rsum = (float*)lds;  // [2(wm)][4(wn)][128] floats = 4KB; all staging/reads done
#pragma unroll
  for (int macc = 0; macc < 8; ++macc) {
#pragma unroll
    for (int reg = 0; reg < 4; ++reg) {
      const int gr = row0 + wm * 128 + macc * 16 + lkg * 4 + reg;
      const int trv = tgt[gr];
      float s = 0.0f;
#pragma unroll
      for (int nf = 0; nf < 4; ++nf) {
        const int gc = jb + (wn & 1) * 64 + nf * 16 + lrow;
        const float p = __builtin_amdgcn_exp2f(fmaf(acc[macc][nf][reg], CEXP, EOFF));
        // n2o: keep diagonal (stands in for the explicit pos column), drop same-label
        // n2n: drop all same-label (diagonal auto-dropped, labels equal)
        const bool keep = (trv != tc[nf]) || (isN2O && gr == gc);
        s += keep ? p : 0.0f;
      }
      s += __shfl_xor(s, 1);
      s += __shfl_xor(s, 2);
      s += __shfl_xor(s, 4);
      s += __shfl_xor(s, 8);
      if (lrow == 0) rsum[(wm * 4 + wn) * 128 + macc * 16 + lkg * 4 + reg] = s;
    }
  }
  asm volatile("s_waitcnt lgkmcnt(0)" ::: "memory");
  barrier_raw();
  if (tid < 256) {
    const int wmg = tid >> 7, rl = tid & 127;
    const float v = rsum[(wmg * 4 + 0) * 128 + rl] + rsum[(wmg * 4 + 1) * 128 + rl] +
                    rsum[(wmg * 4 + 2) * 128 + rl] + rsum[(wmg * 4 + 3) * 128 + rl];
    partial[(size_t)(row0 + tid) * 32 + nt] = v;
  }
}

// ---------------- kernel 3: per-row finalize (32 blocks) ----------------
__global__ __launch_bounds__(256) void k_final(const float* __restrict__ partial,
                                               const float* __restrict__ pos,
                                               float* __restrict__ bsum) {
  const int t = threadIdx.x;
  const int r = blockIdx.x * 128 + (t >> 1);
  const int half = t & 1;
  const float4* p = (const float4*)(partial + (size_t)r * 32 + half * 16);
  float v = 0.0f;
#pragma unroll
  for (int q = 0; q < 4; ++q) {
    const float4 a = p[q];
    v += (a.x + a.y) + (a.z + a.w);
  }
  v += __shfl_xor(v, 1);  // combine the two halves of the row
  float contrib = (half == 0)
                      ? (LSE_BASE + __builtin_amdgcn_logf(v) * LN2 - 100.0f * pos[r])
                      : 0.0f;
  contrib = wave_sum(contrib);
  __shared__ float red[4];
  if ((t & 63) == 0) red[t >> 6] = contrib;
  __syncthreads();
  if (t == 0) bsum[blockIdx.x] = (red[0] + red[1]) + (red[2] + red[3]);
}

// ---------------- kernel 4: mean of 32 block sums ----------------
__global__ __launch_bounds__(64) void k_mean(const float* __restrict__ bsum,
                                             float* __restrict__ out) {
  float s = (threadIdx.x < 32) ? bsum[threadIdx.x] : 0.0f;
  s = wave_sum(s);
  if (threadIdx.x == 0) out[0] = s * (1.0f / (float)BB);
}

extern "C" void kernel_launch(void* const* d_in, const int* in_sizes, int n_in,
                              void* d_out, int out_size, void* d_ws, size_t ws_size,
                              hipStream_t stream) {
  const float* feat = (const float*)d_in[0];
  const float* feat_old = (const float*)d_in[1];
  const int* targets = (const int*)d_in[2];
  float* out = (float*)d_out;
  char* ws = (char*)d_ws;

  u16* fnb = (u16*)ws;                                           // 4 MB
  u16* fob = (u16*)(ws + 4u * 1024 * 1024);                      // 4 MB
  float* pos = (float*)(ws + 8u * 1024 * 1024);                  // 16 KB
  float* partial = (float*)(ws + 8u * 1024 * 1024 + 16 * 1024);  // 512 KB
  float* bsum = (float*)(ws + 8u * 1024 * 1024 + 544 * 1024);    // 128 B

  k_norm<<<BB / 4, 256, 0, stream>>>(feat, feat_old, fnb, fob, pos);
  k_fused<<<512, 512, 0, stream>>>(fnb, fob, targets, partial);
  k_final<<<32, 256, 0, stream>>>(partial, pos, bsum);
  k_mean<<<1, 64, 0, stream>>>(bsum, out);
}